// Round 1
// baseline (199350.171 us; speedup 1.0000x reference)
//
#include <hip/hip_runtime.h>
#include <math.h>

#define HH 2048
#define DD 66
#define TT 4096
#define PRE 64
#define NWG 256
#define RPW 8        // h rows per workgroup (2048/256)
#define FSTRIDE 16   // flag padding: 16 uints = 64B per WG

// Workspace layout (all in d_ws, poisoned 0xAA before each run):
//   float    h1buf[2][HH]      (16 KB)
//   float    h2buf[2][HH]      (16 KB)
//   unsigned flags1[NWG*FSTRIDE] (16 KB)
//   unsigned flags2[NWG*FSTRIDE] (16 KB)
// Equality-based flags (target = t+1) are immune to poison (0xAAAAAAAA != 1..4096).

__device__ __forceinline__ float sigmoidf_(float x) {
  return 1.0f / (1.0f + expf(-x));
}

__device__ __forceinline__ void gbar_wait(unsigned* flags, unsigned target, int tid) {
  unsigned v = __hip_atomic_load(&flags[tid * FSTRIDE], __ATOMIC_RELAXED, __HIP_MEMORY_SCOPE_AGENT);
  while (!__syncthreads_and((int)(v == target))) {
    v = __hip_atomic_load(&flags[tid * FSTRIDE], __ATOMIC_RELAXED, __HIP_MEMORY_SCOPE_AGENT);
  }
}

__global__ __launch_bounds__(256, 1) void lstm_persist(
    const float* __restrict__ y,
    const float* __restrict__ Wih1, const float* __restrict__ Whh1,
    const float* __restrict__ bih1, const float* __restrict__ bhh1,
    const float* __restrict__ Wih2, const float* __restrict__ Whh2,
    const float* __restrict__ bih2, const float* __restrict__ bhh2,
    const float* __restrict__ Wlin, const float* __restrict__ blin,
    float* __restrict__ out,
    float* h1buf, float* h2buf, unsigned* flags1, unsigned* flags2)
{
  __shared__ __align__(16) float ldsH1[HH];
  __shared__ __align__(16) float ldsH2[HH];
  __shared__ float ldsX[DD];
  __shared__ float g1s[4][RPW];
  __shared__ float g2s[4][RPW];
  __shared__ float c1s[RPW];
  __shared__ float c2s[RPW];
  __shared__ float red[4];

  const int tid  = threadIdx.x;
  const int wg   = blockIdx.x;
  const int wave = tid >> 6;
  const int lane = tid & 63;
  const int rowbase = wg * RPW;          // this WG's h-row base
  const int grow0   = wave * HH + rowbase; // first gate row for this wave (i,f,g,o per wave)

  // ---- init ----
  for (int i = tid; i < HH; i += 256) { ldsH1[i] = 0.0f; ldsH2[i] = 0.0f; }
  if (tid < RPW) {
    c1s[tid] = 0.0f; c2s[tid] = 0.0f;
    // zero own slice of h2buf[1] (read as h2_prev at t=0, visible after barrier A(0))
    __hip_atomic_store(&h2buf[HH + rowbase + tid], 0.0f, __ATOMIC_RELAXED, __HIP_MEMORY_SCOPE_AGENT);
  }
  __syncthreads();

  for (int t = 0; t < TT; ++t) {
    //================ phase 1: layer-1 gates (h1 from LDS, set by prev phase-2) ================
    if (tid < DD) ldsX[tid] = y[t * DD + tid];
    __syncthreads();

    {
      float4 acc[RPW];
      #pragma unroll
      for (int r = 0; r < RPW; ++r) acc[r] = make_float4(0.f, 0.f, 0.f, 0.f);
      const float4* h4 = (const float4*)ldsH1;
      #pragma unroll 2
      for (int j = 0; j < 8; ++j) {
        const float4 hv = h4[j * 64 + lane];
        #pragma unroll
        for (int r = 0; r < RPW; ++r) {
          const float4* Wr = (const float4*)(Whh1 + (size_t)(grow0 + r) * HH);
          float4 wv = Wr[j * 64 + lane];
          acc[r].x = fmaf(wv.x, hv.x, acc[r].x);
          acc[r].y = fmaf(wv.y, hv.y, acc[r].y);
          acc[r].z = fmaf(wv.z, hv.z, acc[r].z);
          acc[r].w = fmaf(wv.w, hv.w, acc[r].w);
        }
      }
      #pragma unroll
      for (int r = 0; r < RPW; ++r) {
        const int grow = grow0 + r;
        float a = (acc[r].x + acc[r].y) + (acc[r].z + acc[r].w);
        // input projection: 66-long dot, lanes cover k=lane and k=64+lane (lane<2)
        const float* Xr = Wih1 + (size_t)grow * DD;
        a += Xr[lane] * ldsX[lane];
        if (lane < DD - 64) a += Xr[64 + lane] * ldsX[64 + lane];
        #pragma unroll
        for (int s = 32; s > 0; s >>= 1) a += __shfl_xor(a, s, 64);
        if (lane == 0) g1s[wave][r] = a + bih1[grow] + bhh1[grow];
      }
    }
    __syncthreads();

    if (tid < RPW) {
      float gi = sigmoidf_(g1s[0][tid]);
      float gf = sigmoidf_(g1s[1][tid]);
      float gg = tanhf(g1s[2][tid]);
      float go = sigmoidf_(g1s[3][tid]);
      float c  = fmaf(gf, c1s[tid], gi * gg);
      c1s[tid] = c;
      float h  = go * tanhf(c);
      __hip_atomic_store(&h1buf[(t & 1) * HH + rowbase + tid], h,
                         __ATOMIC_RELAXED, __HIP_MEMORY_SCOPE_AGENT);
    }
    __syncthreads();
    if (tid == 0)
      __hip_atomic_store(&flags1[wg * FSTRIDE], (unsigned)(t + 1),
                         __ATOMIC_RELEASE, __HIP_MEMORY_SCOPE_AGENT);
    gbar_wait(flags1, (unsigned)(t + 1), tid);

    //================ phase 2: layer-2 gates, h2 publish, out_{t-1} ================
    for (int i = tid; i < HH; i += 256) {
      ldsH1[i] = __hip_atomic_load(&h1buf[(t & 1) * HH + i],
                                   __ATOMIC_RELAXED, __HIP_MEMORY_SCOPE_AGENT);
      ldsH2[i] = __hip_atomic_load(&h2buf[((t + 1) & 1) * HH + i],
                                   __ATOMIC_RELAXED, __HIP_MEMORY_SCOPE_AGENT);
    }
    __syncthreads();

    {
      float4 acc[RPW];
      #pragma unroll
      for (int r = 0; r < RPW; ++r) acc[r] = make_float4(0.f, 0.f, 0.f, 0.f);
      const float4* ha = (const float4*)ldsH1;
      const float4* hb = (const float4*)ldsH2;
      #pragma unroll 2
      for (int j = 0; j < 8; ++j) {
        const float4 va = ha[j * 64 + lane];
        const float4 vb = hb[j * 64 + lane];
        #pragma unroll
        for (int r = 0; r < RPW; ++r) {
          const float4* Wa = (const float4*)(Wih2 + (size_t)(grow0 + r) * HH);
          const float4* Wb = (const float4*)(Whh2 + (size_t)(grow0 + r) * HH);
          float4 wa = Wa[j * 64 + lane];
          float4 wb = Wb[j * 64 + lane];
          acc[r].x = fmaf(wa.x, va.x, acc[r].x);
          acc[r].y = fmaf(wa.y, va.y, acc[r].y);
          acc[r].z = fmaf(wa.z, va.z, acc[r].z);
          acc[r].w = fmaf(wa.w, va.w, acc[r].w);
          acc[r].x = fmaf(wb.x, vb.x, acc[r].x);
          acc[r].y = fmaf(wb.y, vb.y, acc[r].y);
          acc[r].z = fmaf(wb.z, vb.z, acc[r].z);
          acc[r].w = fmaf(wb.w, vb.w, acc[r].w);
        }
      }
      #pragma unroll
      for (int r = 0; r < RPW; ++r) {
        const int grow = grow0 + r;
        float a = (acc[r].x + acc[r].y) + (acc[r].z + acc[r].w);
        #pragma unroll
        for (int s = 32; s > 0; s >>= 1) a += __shfl_xor(a, s, 64);
        if (lane == 0) g2s[wave][r] = a + bih2[grow] + bhh2[grow];
      }
    }
    __syncthreads();

    if (tid < RPW) {
      float gi = sigmoidf_(g2s[0][tid]);
      float gf = sigmoidf_(g2s[1][tid]);
      float gg = tanhf(g2s[2][tid]);
      float go = sigmoidf_(g2s[3][tid]);
      float c  = fmaf(gf, c2s[tid], gi * gg);
      c2s[tid] = c;
      float h  = go * tanhf(c);
      __hip_atomic_store(&h2buf[(t & 1) * HH + rowbase + tid], h,
                         __ATOMIC_RELAXED, __HIP_MEMORY_SCOPE_AGENT);
    }
    __syncthreads();
    if (tid == 0)
      __hip_atomic_store(&flags2[wg * FSTRIDE], (unsigned)(t + 1),
                         __ATOMIC_RELEASE, __HIP_MEMORY_SCOPE_AGENT);

    // out_{t-1} = Wlin . h2_{t-1} (+bias); h2_{t-1} is already in ldsH2.
    // Done AFTER our flag store so it overlaps the barrier wait.
    if (wg < DD && t >= PRE + 1) {
      const float4* Wr = (const float4*)(Wlin + (size_t)wg * HH);
      const float4* h4 = (const float4*)ldsH2;
      float p = 0.f;
      #pragma unroll
      for (int j = 0; j < 2; ++j) {
        int idx = tid + j * 256;
        float4 wv = Wr[idx]; float4 hv = h4[idx];
        p += wv.x * hv.x + wv.y * hv.y + wv.z * hv.z + wv.w * hv.w;
      }
      #pragma unroll
      for (int s = 32; s > 0; s >>= 1) p += __shfl_xor(p, s, 64);
      if (lane == 0) red[wave] = p;
      __syncthreads();
      if (tid == 0)
        out[(size_t)(t - 1 - PRE) * DD + wg] = red[0] + red[1] + red[2] + red[3] + blin[wg];
    }

    gbar_wait(flags2, (unsigned)(t + 1), tid);
  }

  //================ epilogue: out for t = TT-1 ================
  if (wg < DD) {
    for (int i = tid; i < HH; i += 256)
      ldsH2[i] = __hip_atomic_load(&h2buf[((TT - 1) & 1) * HH + i],
                                   __ATOMIC_RELAXED, __HIP_MEMORY_SCOPE_AGENT);
    __syncthreads();
    const float4* Wr = (const float4*)(Wlin + (size_t)wg * HH);
    const float4* h4 = (const float4*)ldsH2;
    float p = 0.f;
    #pragma unroll
    for (int j = 0; j < 2; ++j) {
      int idx = tid + j * 256;
      float4 wv = Wr[idx]; float4 hv = h4[idx];
      p += wv.x * hv.x + wv.y * hv.y + wv.z * hv.z + wv.w * hv.w;
    }
    #pragma unroll
    for (int s = 32; s > 0; s >>= 1) p += __shfl_xor(p, s, 64);
    if (lane == 0) red[wave] = p;
    __syncthreads();
    if (tid == 0)
      out[(size_t)(TT - 1 - PRE) * DD + wg] = red[0] + red[1] + red[2] + red[3] + blin[wg];
  }
}

extern "C" void kernel_launch(void* const* d_in, const int* in_sizes, int n_in,
                              void* d_out, int out_size, void* d_ws, size_t ws_size,
                              hipStream_t stream) {
  const float* y    = (const float*)d_in[0];
  const float* Wih1 = (const float*)d_in[1];
  const float* Whh1 = (const float*)d_in[2];
  const float* bih1 = (const float*)d_in[3];
  const float* bhh1 = (const float*)d_in[4];
  const float* Wih2 = (const float*)d_in[5];
  const float* Whh2 = (const float*)d_in[6];
  const float* bih2 = (const float*)d_in[7];
  const float* bhh2 = (const float*)d_in[8];
  const float* Wlin = (const float*)d_in[9];
  const float* blin = (const float*)d_in[10];
  // d_in[11] = pre_output_len (64), compiled in as PRE.
  float* out = (float*)d_out;

  char* ws = (char*)d_ws;
  float*    h1buf  = (float*)(ws);
  float*    h2buf  = (float*)(ws + 2 * HH * sizeof(float));
  unsigned* flags1 = (unsigned*)(ws + 4 * HH * sizeof(float));
  unsigned* flags2 = flags1 + NWG * FSTRIDE;

  void* args[] = { &y, &Wih1, &Whh1, &bih1, &bhh1, &Wih2, &Whh2, &bih2, &bhh2,
                   &Wlin, &blin, &out, &h1buf, &h2buf, &flags1, &flags2 };
  hipLaunchCooperativeKernel((const void*)lstm_persist, dim3(NWG), dim3(256),
                             args, 0, stream);
}